// Round 1
// baseline (461.371 us; speedup 1.0000x reference)
//
#include <hip/hip_runtime.h>

typedef unsigned short u16;
typedef unsigned int   u32;
typedef short s16x8 __attribute__((ext_vector_type(8)));
typedef float f32x4 __attribute__((ext_vector_type(4)));

#define MFMA16(A,B,C) __builtin_amdgcn_mfma_f32_16x16x32_bf16((A),(B),(C),0,0,0)

#define B_   32
#define S_   257
#define E_   1024
#define H_   16
#define D_   64
#define I_   4096
#define M_   (B_*S_)   // 8224

__device__ __forceinline__ u16 f2bf(float f) {
    u32 u = __float_as_uint(f);
    u32 r = u + 0x7fffu + ((u >> 16) & 1u);
    return (u16)(r >> 16);
}
__device__ __forceinline__ float bf2f(u16 b) {
    return __uint_as_float(((u32)b) << 16);
}

__device__ __forceinline__ void gload16(const void* g, void* l) {
    __builtin_amdgcn_global_load_lds(
        (const __attribute__((address_space(1))) u32*)g,
        (__attribute__((address_space(3))) u32*)l, 16, 0, 0);
}

// ---------------- weight fp32 -> bf16 convert (12M elems) ----------------
__global__ __launch_bounds__(256)
void convert_w_kernel(const float* __restrict__ qw, const float* __restrict__ kw,
                      const float* __restrict__ vw, const float* __restrict__ ow,
                      const float* __restrict__ f1, const float* __restrict__ f2,
                      u16* __restrict__ dst)
{
    const int total4 = (12 * 1048576) / 4;
    for (int i = blockIdx.x * 256 + threadIdx.x; i < total4; i += gridDim.x * 256) {
        int e = i * 4;
        int seg = e >> 20;                 // 0..11 (segments are 1M-elem aligned)
        const float* srcp; int off;
        if (seg < 4)      { srcp = (seg == 0 ? qw : seg == 1 ? kw : seg == 2 ? vw : ow); off = e & 1048575; }
        else if (seg < 8) { srcp = f1; off = e - 4 * 1048576; }
        else              { srcp = f2; off = e - 8 * 1048576; }
        float4 v = *(const float4*)(srcp + off);
        ushort4 o;
        o.x = f2bf(v.x); o.y = f2bf(v.y); o.z = f2bf(v.z); o.w = f2bf(v.w);
        *(ushort4*)(dst + e) = o;
    }
}

// ---------------- combined mask table: msum[b][sq][272] bf16 ----------------
__global__ __launch_bounds__(256)
void mask_combine_kernel(const float* __restrict__ am, const float* __restrict__ cm,
                         u16* __restrict__ msum)
{
    const int total = B_ * S_ * 272;
    for (int i = blockIdx.x * 256 + threadIdx.x; i < total; i += gridDim.x * 256) {
        int skv = i % 272;
        int rem = i / 272;
        int sq  = rem % S_;
        int b   = rem / S_;
        float v;
        if (skv < S_) {
            size_t o = ((size_t)b * S_ + sq) * S_ + skv;
            v = am[o] + cm[o];
        } else v = -1e30f;
        msum[i] = f2bf(v);
    }
}

// ---------------- LayerNorm row kernel (1024 cols, 256 thr/row) ----------------
__global__ __launch_bounds__(256)
void ln_kernel(const float* __restrict__ src, const float* __restrict__ gam,
               const float* __restrict__ bet, u16* __restrict__ dst)
{
    int row = blockIdx.x;
    const float4* p = (const float4*)(src + (size_t)row * E_);
    float4 x = p[threadIdx.x];
    float s  = x.x + x.y + x.z + x.w;
    float s2 = x.x * x.x + x.y * x.y + x.z * x.z + x.w * x.w;
#pragma unroll
    for (int xm = 1; xm < 64; xm <<= 1) {
        s  += __shfl_xor(s,  xm, 64);
        s2 += __shfl_xor(s2, xm, 64);
    }
    __shared__ float red[8];
    int wv = threadIdx.x >> 6;
    if ((threadIdx.x & 63) == 0) { red[wv] = s; red[4 + wv] = s2; }
    __syncthreads();
    s  = red[0] + red[1] + red[2] + red[3];
    s2 = red[4] + red[5] + red[6] + red[7];
    float mu  = s * (1.0f / 1024.0f);
    float var = s2 * (1.0f / 1024.0f) - mu * mu;
    float rs  = rsqrtf(var + 1e-5f);
    float4 g  = ((const float4*)gam)[threadIdx.x];
    float4 be = ((const float4*)bet)[threadIdx.x];
    ushort4 o;
    o.x = f2bf((x.x - mu) * rs * g.x + be.x);
    o.y = f2bf((x.y - mu) * rs * g.y + be.y);
    o.z = f2bf((x.z - mu) * rs * g.z + be.z);
    o.w = f2bf((x.w - mu) * rs * g.w + be.w);
    ((ushort4*)dst)[(size_t)row * 256 + threadIdx.x] = o;
}

// ---------------- NT GEMM: C[m][n] = sum_k A[m][k]*B[n][k]  (m97-style) ----------
// MODE 0: fused QKV -> bf16 [B,H,S,D] outputs (q scaled by 1/8 incl. bias)
// MODE 1: f32 out = acc + bias + res
// MODE 2: bf16 out = gelu_tanh(acc + bias)
template<int MODE>
__global__ __launch_bounds__(256)
void gemm_bt(const u16* __restrict__ A,
             const u16* __restrict__ B0, const u16* __restrict__ B1, const u16* __restrict__ B2,
             const float* __restrict__ bias0, const float* __restrict__ bias1, const float* __restrict__ bias2,
             const float* __restrict__ res, float* __restrict__ outF,
             u16* __restrict__ outB0, u16* __restrict__ outB1, u16* __restrict__ outB2,
             int M, int N, int K)
{
    __shared__ u16 As[128 * 32];
    __shared__ u16 Bs[128 * 32];
    const int tid = threadIdx.x, lane = tid & 63, wv = tid >> 6;
    const int mt = blockIdx.y;
    const u16* Bm = B0; const float* bias = bias0; u16* outB = outB0;
    float scl = 1.0f;
    int nt = blockIdx.x;
    if (MODE == 0) {
        int mat = nt >> 3; nt &= 7;
        if (mat == 1)      { Bm = B1; bias = bias1; outB = outB1; }
        else if (mat == 2) { Bm = B2; bias = bias2; outB = outB2; }
        if (mat == 0) scl = 0.125f;   // D^-0.5
    }
    const int m0 = mt * 128, n0 = nt * 128;
    const int lr = lane & 15, lg = lane >> 4;
    const int wm = wv >> 1, wn = wv & 1;

    f32x4 acc[4][4];
#pragma unroll
    for (int i = 0; i < 4; ++i)
#pragma unroll
        for (int j = 0; j < 4; ++j) { f32x4 z = {0.f, 0.f, 0.f, 0.f}; acc[i][j] = z; }

    for (int k0 = 0; k0 < K; k0 += 32) {
#pragma unroll
        for (int i = 0; i < 2; ++i) {
            int c  = i * 256 + tid;
            int r  = c >> 2, cc = (c & 3) << 3;
            int ra = m0 + r; if (ra > M - 1) ra = M - 1;    // clamp M edge
            gload16(A  + (size_t)ra * K + k0 + cc, As + (i * 256 + wv * 64) * 8);
            gload16(Bm + (size_t)(n0 + r) * K + k0 + cc, Bs + (i * 256 + wv * 64) * 8);
        }
        __syncthreads();
        s16x8 af[4], bfr[4];
#pragma unroll
        for (int f = 0; f < 4; ++f) {
            af[f]  = *(const s16x8*)&As[(wm * 64 + f * 16 + lr) * 32 + lg * 8];
            bfr[f] = *(const s16x8*)&Bs[(wn * 64 + f * 16 + lr) * 32 + lg * 8];
        }
#pragma unroll
        for (int fm = 0; fm < 4; ++fm)
#pragma unroll
            for (int fn = 0; fn < 4; ++fn)
                acc[fm][fn] = MFMA16(af[fm], bfr[fn], acc[fm][fn]);
        __syncthreads();
    }

    float biasv[4];
#pragma unroll
    for (int fn = 0; fn < 4; ++fn) biasv[fn] = bias[n0 + wn * 64 + fn * 16 + lr];

#pragma unroll
    for (int fm = 0; fm < 4; ++fm) {
#pragma unroll
        for (int r = 0; r < 4; ++r) {
            int row = m0 + wm * 64 + fm * 16 + lg * 4 + r;
            if (row >= M) continue;
            if (MODE == 0) {
                int bb = row / S_;
                int ss = row - bb * S_;
#pragma unroll
                for (int fn = 0; fn < 4; ++fn) {
                    int col = n0 + wn * 64 + fn * 16 + lr;
                    int hh = col >> 6, dd = col & 63;
                    float v = (acc[fm][fn][r] + biasv[fn]) * scl;
                    outB[(((size_t)bb * H_ + hh) * S_ + ss) * D_ + dd] = f2bf(v);
                }
            } else if (MODE == 1) {
                size_t base = (size_t)row * N;
#pragma unroll
                for (int fn = 0; fn < 4; ++fn) {
                    int col = n0 + wn * 64 + fn * 16 + lr;
                    outF[base + col] = acc[fm][fn][r] + biasv[fn] + res[base + col];
                }
            } else {
                size_t base = (size_t)row * N;
#pragma unroll
                for (int fn = 0; fn < 4; ++fn) {
                    int col = n0 + wn * 64 + fn * 16 + lr;
                    float x = acc[fm][fn][r] + biasv[fn];
                    float u = 0.7978845608028654f * (x + 0.044715f * x * x * x);
                    float t = tanhf(u);
                    outB[base + col] = f2bf(0.5f * x * (1.0f + t));
                }
            }
        }
    }
}

// ---------------- fused attention: one WG per (b,h) ----------------
// K in LDS [272][72] (stride 72 => 144B rows, 16B aligned, 2-way banks)
// V^T in LDS [64][296]; P round-trip via 1KB wave-private LDS.
__global__ __launch_bounds__(256)
void attn_kernel(const u16* __restrict__ qg_, const u16* __restrict__ kg_,
                 const u16* __restrict__ vg_, const u16* __restrict__ msum,
                 u16* __restrict__ ctx)
{
    __shared__ u16 Ks[272 * 72];     // 39168 B
    __shared__ u16 Vt[64 * 296];     // 37888 B
    __shared__ u16 Ps[4][16 * 32];   //  4096 B  (total 81152 B -> 2 WG/CU)
    const int bh = blockIdx.x;
    const int b = bh >> 4, hh = bh & 15;
    const u16* kg = kg_ + (size_t)bh * (S_ * D_);
    const u16* vg = vg_ + (size_t)bh * (S_ * D_);
    const u16* qg = qg_ + (size_t)bh * (S_ * D_);
    const int tid = threadIdx.x, lane = tid & 63, wv = tid >> 6;

    // stage K (row-major, padded stride 72)
    for (int c = tid; c < (S_ * D_) / 8; c += 256) {      // 2056 chunks
        int s = c >> 3, d8 = (c & 7) << 3;
        s16x8 val = *(const s16x8*)(kg + s * 64 + d8);
        *(s16x8*)&Ks[s * 72 + d8] = val;
    }
    for (int idx = tid; idx < 15 * 64; idx += 256) {      // zero rows 257..271
        int rr = 257 + (idx >> 6), cc = idx & 63;
        Ks[rr * 72 + cc] = 0;
    }
    // stage V^T
    for (int c = tid; c < (S_ * D_) / 8; c += 256) {
        int s = c >> 3, d8 = (c & 7) << 3;
        s16x8 val = *(const s16x8*)(vg + s * 64 + d8);
#pragma unroll
        for (int j = 0; j < 8; ++j) Vt[(d8 + j) * 296 + s] = (u16)val[j];
    }
    for (int idx = tid; idx < 64 * 39; idx += 256) {      // zero cols 257..295
        int dd = idx / 39, cc = 257 + idx % 39;
        Vt[dd * 296 + cc] = 0;
    }
    __syncthreads();

    const int lr = lane & 15, lg = lane >> 4;
    for (int qb = wv; qb < 17; qb += 4) {
        const int q0 = qb * 16;
        int qrow = q0 + lr; if (qrow > S_ - 1) qrow = S_ - 1;
        s16x8 aq0 = *(const s16x8*)(qg + qrow * 64 + lg * 8);
        s16x8 aq1 = *(const s16x8*)(qg + qrow * 64 + 32 + lg * 8);

        f32x4 sc[17];
#pragma unroll
        for (int t = 0; t < 17; ++t) { f32x4 z = {0.f, 0.f, 0.f, 0.f}; sc[t] = z; }
#pragma unroll
        for (int t = 0; t < 17; ++t) {
            s16x8 b0 = *(const s16x8*)&Ks[(t * 16 + lr) * 72 + lg * 8];
            s16x8 b1 = *(const s16x8*)&Ks[(t * 16 + lr) * 72 + 32 + lg * 8];
            sc[t] = MFMA16(aq0, b0, sc[t]);
            sc[t] = MFMA16(aq1, b1, sc[t]);
        }
        // add combined mask (includes -1e30 for cols>=257), row max
        float mx[4] = {-3e38f, -3e38f, -3e38f, -3e38f};
#pragma unroll
        for (int r = 0; r < 4; ++r) {
            int sq = q0 + lg * 4 + r; if (sq > S_ - 1) sq = S_ - 1;
            const u16* mrow = msum + ((size_t)b * S_ + sq) * 272;
#pragma unroll
            for (int t = 0; t < 17; ++t) {
                sc[t][r] += bf2f(mrow[t * 16 + lr]);
                mx[r] = fmaxf(mx[r], sc[t][r]);
            }
        }
#pragma unroll
        for (int r = 0; r < 4; ++r) {
#pragma unroll
            for (int xm = 1; xm <= 8; xm <<= 1)
                mx[r] = fmaxf(mx[r], __shfl_xor(mx[r], xm, 64));
        }
        float sum[4] = {0.f, 0.f, 0.f, 0.f};
#pragma unroll
        for (int t = 0; t < 17; ++t)
#pragma unroll
            for (int r = 0; r < 4; ++r) {
                float e = __expf(sc[t][r] - mx[r]);
                sc[t][r] = e; sum[r] += e;
            }
#pragma unroll
        for (int r = 0; r < 4; ++r) {
#pragma unroll
            for (int xm = 1; xm <= 8; xm <<= 1)
                sum[r] += __shfl_xor(sum[r], xm, 64);
        }

        // PV: 9 chunks of 32 kv via wave-private P staging
        f32x4 ac[4];
#pragma unroll
        for (int nt = 0; nt < 4; ++nt) { f32x4 z = {0.f, 0.f, 0.f, 0.f}; ac[nt] = z; }
        u16* myP = &Ps[wv][0];
#pragma unroll
        for (int kc = 0; kc < 9; ++kc) {
#pragma unroll
            for (int tt = 0; tt < 2; ++tt) {
                const int t = kc * 2 + tt;
#pragma unroll
                for (int r = 0; r < 4; ++r) {
                    float pv = (t < 17) ? sc[(t < 17) ? t : 0][r] : 0.f;
                    myP[(lg * 4 + r) * 32 + tt * 16 + lr] = f2bf(pv);
                }
            }
            s16x8 pa = *(const s16x8*)&myP[lr * 32 + lg * 8];
#pragma unroll
            for (int nt = 0; nt < 4; ++nt) {
                s16x8 bv = *(const s16x8*)&Vt[(nt * 16 + lr) * 296 + kc * 32 + lg * 8];
                ac[nt] = MFMA16(pa, bv, ac[nt]);
            }
        }
#pragma unroll
        for (int r = 0; r < 4; ++r) {
            int sq = q0 + lg * 4 + r;
            if (sq < S_) {
                float rd = 1.0f / sum[r];
                size_t base = (((size_t)b * S_ + sq) * H_ + hh) * D_;
#pragma unroll
                for (int nt = 0; nt < 4; ++nt)
                    ctx[base + nt * 16 + lr] = f2bf(ac[nt][r] * rd);
            }
        }
    }
}

// ---------------- launch ----------------
extern "C" void kernel_launch(void* const* d_in, const int* in_sizes, int n_in,
                              void* d_out, int out_size, void* d_ws, size_t ws_size,
                              hipStream_t stream)
{
    const float* hid   = (const float*)d_in[0];
    const float* am    = (const float*)d_in[1];
    const float* cm    = (const float*)d_in[2];
    const float* ln1w  = (const float*)d_in[3];
    const float* ln1b  = (const float*)d_in[4];
    const float* qw    = (const float*)d_in[5];
    const float* qbias = (const float*)d_in[6];
    const float* kw    = (const float*)d_in[7];
    const float* kbias = (const float*)d_in[8];
    const float* vw    = (const float*)d_in[9];
    const float* vbias = (const float*)d_in[10];
    const float* ow    = (const float*)d_in[11];
    const float* obias = (const float*)d_in[12];
    const float* ln2w  = (const float*)d_in[13];
    const float* ln2b  = (const float*)d_in[14];
    const float* f1w   = (const float*)d_in[15];
    const float* f1b   = (const float*)d_in[16];
    const float* f2w   = (const float*)d_in[17];
    const float* f2b   = (const float*)d_in[18];
    float* out = (float*)d_out;

    const size_t ME = (size_t)M_ * E_;      // 8,421,376
    u16* Wq   = (u16*)d_ws;                 // 1M elems each for q,k,v,o
    u16* Wk   = Wq + 1048576;
    u16* Wv   = Wk + 1048576;
    u16* Wo   = Wv + 1048576;
    u16* Wf1  = Wo + 1048576;               // 4M
    u16* Wf2  = Wf1 + 4 * 1048576;          // 4M
    u16* xln  = Wf2 + 4 * 1048576;          // M x E bf16 (reused as x2)
    u16* qb_  = xln + ME;
    u16* kb_  = qb_ + ME;
    u16* vb_  = kb_ + ME;
    u16* ctx  = vb_ + ME;
    float* hbuf = (float*)(ctx + ME);       // M x E f32
    u16* msum = (u16*)(hbuf + ME);          // B*S*272 bf16
    u16* act  = qb_;                        // reuse q..ctx region = M x I bf16 (exact)
    u16* x2   = xln;

    convert_w_kernel<<<3072, 256, 0, stream>>>(qw, kw, vw, ow, f1w, f2w, Wq);
    mask_combine_kernel<<<8736, 256, 0, stream>>>(am, cm, msum);
    ln_kernel<<<M_, 256, 0, stream>>>(hid, ln1w, ln1b, xln);
    gemm_bt<0><<<dim3(24, 65), 256, 0, stream>>>(xln, Wq, Wk, Wv, qbias, kbias, vbias,
                                                 nullptr, nullptr, qb_, kb_, vb_,
                                                 M_, E_, E_);
    attn_kernel<<<512, 256, 0, stream>>>(qb_, kb_, vb_, msum, ctx);
    gemm_bt<1><<<dim3(8, 65), 256, 0, stream>>>(ctx, Wo, nullptr, nullptr, obias, nullptr, nullptr,
                                                hid, hbuf, nullptr, nullptr, nullptr,
                                                M_, E_, E_);
    ln_kernel<<<M_, 256, 0, stream>>>(hbuf, ln2w, ln2b, x2);
    gemm_bt<2><<<dim3(32, 65), 256, 0, stream>>>(x2, Wf1, nullptr, nullptr, f1b, nullptr, nullptr,
                                                 nullptr, nullptr, act, nullptr, nullptr,
                                                 M_, I_, E_);
    gemm_bt<1><<<dim3(8, 65), 256, 0, stream>>>(act, Wf2, nullptr, nullptr, f2b, nullptr, nullptr,
                                                hbuf, out, nullptr, nullptr, nullptr,
                                                M_, E_, I_);
}